// Round 4
// baseline (371.977 us; speedup 1.0000x reference)
//
#include <hip/hip_runtime.h>
#include <cmath>

#define B_ 4
#define T_ 8192
#define C_ 256
#define E_ 8
#define M_ (B_*T_)

typedef __bf16 bf16x8 __attribute__((ext_vector_type(8)));
typedef float  f32x16 __attribute__((ext_vector_type(16)));

typedef const __attribute__((address_space(1))) unsigned int* gas_t;
typedef __attribute__((address_space(3))) unsigned int* las_t;

static __device__ __forceinline__ unsigned short f2bf(float f) {
    union { float fv; unsigned u; } v; v.fv = f;
    unsigned r = v.u + 0x7FFFu + ((v.u >> 16) & 1u);
    return (unsigned short)(r >> 16);
}

// Abramowitz-Stegun 7.1.26: |err| <= 1.5e-7
static __device__ __forceinline__ float fast_erf(float x) {
    float ax = fabsf(x);
    float t = __builtin_amdgcn_rcpf(1.0f + 0.3275911f * ax);
    float p = ((((1.061405429f * t - 1.453152027f) * t) + 1.421413741f) * t - 0.284496736f) * t + 0.254829592f;
    float y = 1.0f - p * t * __expf(-ax * ax);
    return copysignf(y, x);
}

static __device__ __forceinline__ float gelu_f(float x) {
    return 0.5f * x * (1.0f + fast_erf(x * 0.7071067811865476f));
}

static __device__ __forceinline__ f32x16 mfma32(bf16x8 a, bf16x8 b, f32x16 c) {
    return __builtin_amdgcn_mfma_f32_32x32x16_bf16(a, b, c, 0, 0, 0);
}

// stage one 16KB weight chunk [256 cols][32 k] bf16 into LDS, bank-swizzled.
// LDS slot s (16B units) holds global (col,kseg) with s = (col*4+kseg) ^ ((col>>1)&7).
// LDS dest stays linear (global_load_lds constraint); source address pre-swizzled.
static __device__ __forceinline__ void stage_swz(const unsigned short* __restrict__ src,
                                                 unsigned short* lds_base, int tid) {
#pragma unroll
    for (int i = 0; i < 4; i++) {
        int s = i * 256 + tid;
        int m = (s >> 3) & 7;
        int low = (s & 7) ^ m;
        int col = ((s >> 3) << 1) | (low >> 2);
        int kseg = low & 3;
        const unsigned short* gp = src + (col << 8) + (kseg << 3);
        unsigned short* lp = lds_base + ((i * 256 + (tid & ~63)) << 3);
        __builtin_amdgcn_global_load_lds((gas_t)(const void*)gp, (las_t)(void*)lp, 16, 0, 0);
    }
}

// ---------------- prep kernels ----------------

// w1t[e][c][k] = W1[e][k][c], k in [0,256)  (tiled coalesced transpose)
__global__ void k_w1t(const float* __restrict__ W1, unsigned short* __restrict__ w1t) {
    __shared__ float tile[64][65];
    int e = blockIdx.x >> 4, kt = (blockIdx.x >> 2) & 3, ct = blockIdx.x & 3;
    int k0 = kt << 6, c0 = ct << 6;
    const float* src = W1 + ((size_t)e << 18) + ((size_t)k0 << 8) + c0;
    int r = threadIdx.x >> 6, col = threadIdx.x & 63;
#pragma unroll
    for (int i = 0; i < 16; i++)
        tile[r + i * 4][col] = src[(size_t)(r + i * 4) * 256 + col];
    __syncthreads();
    unsigned short* dst = w1t + (e << 16) + (c0 << 8) + k0;
#pragma unroll
    for (int i = 0; i < 16; i++)
        dst[(r + i * 4) * 256 + col] = f2bf(tile[col][r + i * 4]);
}

// w2t[e][f][c] = W2[e][c][f]
__global__ void k_w2t(const float* __restrict__ W2, unsigned short* __restrict__ w2t) {
    __shared__ float tile[64][65];
    int e = blockIdx.x >> 4, ct = (blockIdx.x >> 2) & 3, ft = blockIdx.x & 3;
    int c0 = ct << 6, f0 = ft << 6;
    const float* src = W2 + ((size_t)e << 16) + ((size_t)c0 << 8) + f0;
    int r = threadIdx.x >> 6, col = threadIdx.x & 63;
#pragma unroll
    for (int i = 0; i < 16; i++)
        tile[r + i * 4][col] = src[(size_t)(r + i * 4) * 256 + col];
    __syncthreads();
    unsigned short* dst = w2t + (e << 16) + (f0 << 8) + c0;
#pragma unroll
    for (int i = 0; i < 16; i++)
        dst[(r + i * 4) * 256 + col] = f2bf(tile[col][r + i * 4]);
}

// v2[e][c] = sum_f W2[e,c,f]*We[e,f];  c2[e] = sum_f b2[e,f]*We[e,f] + be[e]
__global__ void k_v2(const float* __restrict__ W2, const float* __restrict__ We,
                     const float* __restrict__ b2, const float* __restrict__ be,
                     float* __restrict__ v2, float* __restrict__ c2) {
    __shared__ float sm[4];
    int e = blockIdx.x >> 8, c = blockIdx.x & 255, f = threadIdx.x;
    float wef = We[(e << 8) + f];
    float v = W2[((((e << 8) + c) << 8)) + f] * wef;
#pragma unroll
    for (int m = 32; m >= 1; m >>= 1) v += __shfl_xor(v, m);
    if ((f & 63) == 0) sm[f >> 6] = v;
    __syncthreads();
    if (f == 0) v2[(e << 8) + c] = sm[0] + sm[1] + sm[2] + sm[3];
    if (c == 0) {
        __syncthreads();
        float u = b2[(e << 8) + f] * wef;
#pragma unroll
        for (int m = 32; m >= 1; m >>= 1) u += __shfl_xor(u, m);
        if ((f & 63) == 0) sm[f >> 6] = u;
        __syncthreads();
        if (f == 0) c2[e] = sm[0] + sm[1] + sm[2] + sm[3] + be[e];
    }
}

// ---------------- LN + masked stats (+ x -> bf16 conversion fused) ----------------

__global__ void k_stats(const float* __restrict__ x, const int* __restrict__ mask,
                        const float* __restrict__ lnw, const float* __restrict__ lnb,
                        float* __restrict__ S1, float* __restrict__ S2, float* __restrict__ ncnt,
                        unsigned short* __restrict__ xb) {
    int b = blockIdx.x >> 6;
    int chunk = blockIdx.x & 63;
    int wid = threadIdx.x >> 6, lane = threadIdx.x & 63;
    int c0 = lane << 2;
    float4 w4 = *reinterpret_cast<const float4*>(lnw + c0);
    float4 b4 = *reinterpret_cast<const float4*>(lnb + c0);
    float a1[4] = {0,0,0,0}, a2[4] = {0,0,0,0};
    int cnt = 0;
    int tbase = chunk * 128;
    for (int r = wid; r < 128; r += 4) {
        int row = b * T_ + tbase + r;
        float4 xv = *reinterpret_cast<const float4*>(x + (size_t)row * C_ + c0);
        ushort4 o;
        o.x = f2bf(xv.x); o.y = f2bf(xv.y); o.z = f2bf(xv.z); o.w = f2bf(xv.w);
        *reinterpret_cast<ushort4*>(xb + (size_t)row * C_ + c0) = o;
        float s1 = xv.x + xv.y + xv.z + xv.w;
        float s2 = xv.x*xv.x + xv.y*xv.y + xv.z*xv.z + xv.w*xv.w;
#pragma unroll
        for (int m = 1; m < 64; m <<= 1) { s1 += __shfl_xor(s1, m); s2 += __shfl_xor(s2, m); }
        if (mask[row]) {
            float mu = s1 * (1.f / C_);
            float var = s2 * (1.f / C_) - mu * mu;
            float rs = rsqrtf(var + 1e-5f);
            float hv;
            hv = (xv.x - mu) * rs * w4.x + b4.x; a1[0] += hv; a2[0] += hv * hv;
            hv = (xv.y - mu) * rs * w4.y + b4.y; a1[1] += hv; a2[1] += hv * hv;
            hv = (xv.z - mu) * rs * w4.z + b4.z; a1[2] += hv; a2[2] += hv * hv;
            hv = (xv.w - mu) * rs * w4.w + b4.w; a1[3] += hv; a2[3] += hv * hv;
            cnt++;
        }
    }
    __shared__ float red[4][256];
    __shared__ int rc[4];
#pragma unroll
    for (int j = 0; j < 4; j++) red[wid][c0 + j] = a1[j];
    if (lane == 0) rc[wid] = cnt;
    __syncthreads();
    int ch = threadIdx.x;
    float s = red[0][ch] + red[1][ch] + red[2][ch] + red[3][ch];
    atomicAdd(&S1[(b << 8) + ch], s);
    if (threadIdx.x == 0) atomicAdd(&ncnt[b], (float)(rc[0] + rc[1] + rc[2] + rc[3]));
    __syncthreads();
#pragma unroll
    for (int j = 0; j < 4; j++) red[wid][c0 + j] = a2[j];
    __syncthreads();
    s = red[0][ch] + red[1][ch] + red[2][ch] + red[3][ch];
    atomicAdd(&S2[(b << 8) + ch], s);
}

__global__ void k_stats_fin(const float* __restrict__ S1, const float* __restrict__ S2,
                            const float* __restrict__ ncnt, float* __restrict__ stats) {
    int b = blockIdx.x, c = threadIdx.x;
    float n = fmaxf(ncnt[b], 1.f);
    float mean = S1[(b << 8) + c] / n;
    float var_b = fmaxf(S2[(b << 8) + c] / n - mean * mean, 0.f);
    float var_u = (n > 1.f) ? (var_b * (n / fmaxf(n - 1.f, 1e-9f))) : var_b;
    float std_u = fmaxf(sqrtf(var_u), 1e-9f);
    stats[b * 768 + 0 * 256 + c] = mean;
    stats[b * 768 + 1 * 256 + c] = std_u;
    stats[b * 768 + 2 * 256 + c] = var_u;
}

__global__ void k_bias(const float* __restrict__ W1, const float* __restrict__ b1,
                       const float* __restrict__ stats, float* __restrict__ bias) {
    int b = blockIdx.x >> 3, e = blockIdx.x & 7, c = threadIdx.x;
    __shared__ float sm[768];
    for (int i = threadIdx.x; i < 768; i += 256) sm[i] = stats[b * 768 + i];
    __syncthreads();
    const float* w = W1 + (size_t)e * 1024 * 256;
    float acc = b1[(e << 8) + c];
#pragma unroll 4
    for (int j = 0; j < 256; j++) {
        acc += sm[j]       * w[(256 + j) * 256 + c];
        acc += sm[256 + j] * w[(512 + j) * 256 + c];
        acc += sm[512 + j] * w[(768 + j) * 256 + c];
    }
    bias[((b << 3) + e) * 256 + c] = acc;
}

// ---------------- fused: GEMM1 + gelu + energies + online softmax + GEMM2 ----------------
// block = 64 rows, 4 waves (2m x 2n), 32x32x16 MFMA; wave = 32 rows x 128 cols.

__global__ __launch_bounds__(256, 2) void k_fused(
    const unsigned short* __restrict__ xb, const unsigned short* __restrict__ w1t,
    const unsigned short* __restrict__ w2t, const float* __restrict__ bias,
    const float* __restrict__ v2, const float* __restrict__ c2,
    const int* __restrict__ mask, const float* __restrict__ b2,
    const float* __restrict__ log_beta, const float* __restrict__ prior,
    float* __restrict__ out) {
    __shared__ unsigned short stg[2][8192];   // 2 x 16KB weight chunks (swizzled)
    __shared__ unsigned short h1s[16384];     // [64][256] bf16, row-swizzled
    __shared__ float b2s[2048];               // [8][256]
    __shared__ float nbs[64][8];
    __shared__ float enp[2][64];
    __shared__ float rs_[64], us_[64], sinv_[64];

    int row0 = blockIdx.x << 6;
    int b = row0 >> 13;
    int tid = threadIdx.x;
    int w = tid >> 6, lane = tid & 63;
    int mw = w >> 1, nw = w & 1;
    int nwo = nw << 7;                        // wave's column base (N-half)
    int c_ = lane & 31, hi = lane >> 5;

    for (int i = tid; i < 2048; i += 256) b2s[i] = b2[i];
    int mreg = 0; float m_run = -3.0e38f; float beta = 0.f;
    if (tid < 64) { mreg = mask[row0 + tid]; beta = __expf(log_beta[0]); }

    // A fragments: wave's 32 rows, K=256 -> 16 frags of 16k
    const unsigned short* arow = xb + (size_t)(row0 + (mw << 5) + c_) * C_;
    bf16x8 areg[16];
#pragma unroll
    for (int kf = 0; kf < 16; kf++)
        areg[kf] = *reinterpret_cast<const bf16x8*>(arow + (kf << 4) + (hi << 3));

    f32x16 acc2[4], accG[4];
#pragma unroll
    for (int nt = 0; nt < 4; nt++)
#pragma unroll
        for (int r = 0; r < 16; r++) acc2[nt][r] = 0.f;

    stage_swz(w1t, stg[0], tid);
    __syncthreads();

    int pc = 0;
    for (int e = 0; e < E_; e++) {
        // ---- GEMM1: accG = x @ W1x + bias_fold ----
        const float* bre = bias + (((b << 3) + e) << 8);
#pragma unroll
        for (int nt = 0; nt < 4; nt++) {
            float bv = bre[nwo + (nt << 5) + c_];
#pragma unroll
            for (int r = 0; r < 16; r++) accG[nt][r] = bv;
        }
#pragma unroll
        for (int kk = 0; kk < 8; kk++) {
            int nc = pc + 1;
            if (nc < 128) {
                const unsigned short* nsrc = (((nc >> 3) & 1) ? w2t : w1t) + ((nc >> 4) << 16) + ((nc & 7) << 5);
                stage_swz(nsrc, stg[nc & 1], tid);
            }
            const unsigned short* bs = stg[pc & 1];
#pragma unroll
            for (int kf = 0; kf < 2; kf++) {
                bf16x8 a = areg[(kk << 1) + kf];
#pragma unroll
                for (int nt = 0; nt < 4; nt++) {
                    int col = nwo + (nt << 5) + c_;
                    int slot = ((col << 2) + (kf << 1) + hi) ^ ((c_ >> 1) & 7);
                    bf16x8 bf = *reinterpret_cast<const bf16x8*>(bs + (slot << 3));
                    accG[nt] = mfma32(a, bf, accG[nt]);
                }
            }
            __syncthreads();
            pc++;
        }
        // ---- gelu (in place) + energy partials ----
        float v2v[4];
#pragma unroll
        for (int nt = 0; nt < 4; nt++) v2v[nt] = v2[(e << 8) + nwo + (nt << 5) + c_];
        float epr[16];
#pragma unroll
        for (int r = 0; r < 16; r++) {
            float sum = 0.f;
#pragma unroll
            for (int nt = 0; nt < 4; nt++) {
                float g = gelu_f(accG[nt][r]);
                accG[nt][r] = g;
                sum += g * v2v[nt];
            }
            epr[r] = sum;
        }
#pragma unroll
        for (int m = 1; m < 32; m <<= 1)
#pragma unroll
            for (int r = 0; r < 16; r++) epr[r] += __shfl_xor(epr[r], m);
        // write unscaled gelu(h1) to LDS (row-swizzled), and energy partials
#pragma unroll
        for (int r = 0; r < 16; r++) {
            int rowl = (mw << 5) + (r & 3) + ((r >> 2) << 3) + (hi << 2);
#pragma unroll
            for (int nt = 0; nt < 4; nt++) {
                int col = nwo + (nt << 5) + c_;
                int byteoff = ((rowl << 9) + (col << 1)) ^ ((rowl & 7) << 4);
                *reinterpret_cast<unsigned short*>(reinterpret_cast<char*>(h1s) + byteoff) = f2bf(accG[nt][r]);
            }
            if (c_ == 0) enp[nw][rowl] = epr[r];
        }
        __syncthreads();
        // ---- online softmax update (threads 0..63, row = tid) ----
        if (tid < 64) {
            float en = enp[0][tid] + enp[1][tid] + c2[e];
            float nb = -beta * (en + prior[e]);
            nbs[tid][e] = nb;
            float mn = fmaxf(m_run, nb);
            rs_[tid] = __expf(m_run - mn);
            us_[tid] = __expf(nb - mn);
            m_run = mn;
        }
        __syncthreads();
        // ---- GEMM2: accG = gelu_h1 @ W2 + b2 ----
#pragma unroll
        for (int nt = 0; nt < 4; nt++) {
            float bv = b2s[(e << 8) + nwo + (nt << 5) + c_];
#pragma unroll
            for (int r = 0; r < 16; r++) accG[nt][r] = bv;
        }
        int rowA = (mw << 5) + c_;
        int rswz = (rowA & 7) << 4;
        const char* h1b = reinterpret_cast<const char*>(h1s) + (rowA << 9);
#pragma unroll
        for (int kk = 0; kk < 8; kk++) {
            int nc = pc + 1;
            if (nc < 128) {
                const unsigned short* nsrc = (((nc >> 3) & 1) ? w2t : w1t) + ((nc >> 4) << 16) + ((nc & 7) << 5);
                stage_swz(nsrc, stg[nc & 1], tid);
            }
            const unsigned short* bs = stg[pc & 1];
#pragma unroll
            for (int kf = 0; kf < 2; kf++) {
                int k2 = (kk << 6) + (kf << 5) + (hi << 4);
                bf16x8 a2 = *reinterpret_cast<const bf16x8*>(h1b + (k2 ^ rswz));
#pragma unroll
                for (int nt = 0; nt < 4; nt++) {
                    int col = nwo + (nt << 5) + c_;
                    int slot = ((col << 2) + (kf << 1) + hi) ^ ((c_ >> 1) & 7);
                    bf16x8 bf = *reinterpret_cast<const bf16x8*>(bs + (slot << 3));
                    accG[nt] = mfma32(a2, bf, accG[nt]);
                }
            }
            __syncthreads();
            pc++;
        }
        // ---- merge: acc2 = acc2*r + u*accG ----
#pragma unroll
        for (int r = 0; r < 16; r++) {
            int rowl = (mw << 5) + (r & 3) + ((r >> 2) << 3) + (hi << 2);
            float rr = rs_[rowl];
            float uu = us_[rowl];
#pragma unroll
            for (int nt = 0; nt < 4; nt++)
                acc2[nt][r] = acc2[nt][r] * rr + uu * accG[nt][r];
        }
    }
    // ---- epilogue: normalize by partition function, mask ----
    if (tid < 64) {
        float s = 0.f;
#pragma unroll
        for (int e = 0; e < 8; e++) s += __expf(nbs[tid][e] - m_run);
        sinv_[tid] = mreg ? (1.0f / s) : 0.f;
    }
    __syncthreads();
#pragma unroll
    for (int r = 0; r < 16; r++) {
        int rowl = (mw << 5) + (r & 3) + ((r >> 2) << 3) + (hi << 2);
        float si = sinv_[rowl];
        float* orow = out + (size_t)(row0 + rowl) * C_;
#pragma unroll
        for (int nt = 0; nt < 4; nt++)
            orow[nwo + (nt << 5) + c_] = acc2[nt][r] * si;
    }
}

// ---------------- launch ----------------

extern "C" void kernel_launch(void* const* d_in, const int* in_sizes, int n_in,
                              void* d_out, int out_size, void* d_ws, size_t ws_size,
                              hipStream_t stream) {
    (void)in_sizes; (void)n_in; (void)out_size; (void)ws_size;
    const float* x        = (const float*)d_in[0];
    const int*   mask     = (const int*)d_in[1];
    const float* lnw      = (const float*)d_in[2];
    const float* lnb      = (const float*)d_in[3];
    const float* W1       = (const float*)d_in[4];
    const float* b1       = (const float*)d_in[5];
    const float* W2       = (const float*)d_in[6];
    const float* b2       = (const float*)d_in[7];
    const float* We       = (const float*)d_in[8];
    const float* be       = (const float*)d_in[9];
    const float* log_beta = (const float*)d_in[10];
    const float* prior    = (const float*)d_in[11];
    float* out = (float*)d_out;
    char* ws = (char*)d_ws;

    constexpr size_t OFF_XB    = 0;                       // 16 MB
    constexpr size_t OFF_W1T   = 16777216;                // 1 MB
    constexpr size_t OFF_W2T   = 17825792;                // 1 MB
    constexpr size_t OFF_V2    = 18874368;                // 8 KB
    constexpr size_t OFF_C2    = 18882560;                // 32 B
    constexpr size_t OFF_S1    = 18882592;                // 4 KB
    constexpr size_t OFF_S2    = 18886688;                // 4 KB
    constexpr size_t OFF_N     = 18890784;                // 16 B
    constexpr size_t OFF_STATS = 18890800;                // 12 KB
    constexpr size_t OFF_BIAS  = 18903088;                // 32 KB

    unsigned short* xb  = (unsigned short*)(ws + OFF_XB);
    unsigned short* w1t = (unsigned short*)(ws + OFF_W1T);
    unsigned short* w2t = (unsigned short*)(ws + OFF_W2T);
    float* v2    = (float*)(ws + OFF_V2);
    float* c2    = (float*)(ws + OFF_C2);
    float* S1    = (float*)(ws + OFF_S1);
    float* S2    = (float*)(ws + OFF_S2);
    float* ncnt  = (float*)(ws + OFF_N);
    float* stats = (float*)(ws + OFF_STATS);
    float* bias  = (float*)(ws + OFF_BIAS);

    hipMemsetAsync(ws + OFF_S1, 0, 4096 + 4096 + 16, stream);

    k_w1t<<<128, 256, 0, stream>>>(W1, w1t);
    k_w2t<<<128, 256, 0, stream>>>(W2, w2t);
    k_v2<<<2048, 256, 0, stream>>>(W2, We, b2, be, v2, c2);
    k_stats<<<256, 256, 0, stream>>>(x, mask, lnw, lnb, S1, S2, ncnt, xb);
    k_stats_fin<<<4, 256, 0, stream>>>(S1, S2, ncnt, stats);
    k_bias<<<32, 256, 0, stream>>>(W1, b1, stats, bias);
    k_fused<<<512, 256, 0, stream>>>(xb, w1t, w2t, bias, v2, c2, mask, b2, log_beta, prior, out);
}

// Round 5
// 369.230 us; speedup vs baseline: 1.0074x; 1.0074x over previous
//
#include <hip/hip_runtime.h>
#include <cmath>

#define B_ 4
#define T_ 8192
#define C_ 256
#define E_ 8
#define M_ (B_*T_)

typedef __bf16 bf16x8 __attribute__((ext_vector_type(8)));
typedef float  f32x16 __attribute__((ext_vector_type(16)));

typedef const __attribute__((address_space(1))) unsigned int* gas_t;
typedef __attribute__((address_space(3))) unsigned int* las_t;

static __device__ __forceinline__ unsigned short f2bf(float f) {
    union { float fv; unsigned u; } v; v.fv = f;
    unsigned r = v.u + 0x7FFFu + ((v.u >> 16) & 1u);
    return (unsigned short)(r >> 16);
}

// Abramowitz-Stegun 7.1.26: |err| <= 1.5e-7
static __device__ __forceinline__ float fast_erf(float x) {
    float ax = fabsf(x);
    float t = __builtin_amdgcn_rcpf(1.0f + 0.3275911f * ax);
    float p = ((((1.061405429f * t - 1.453152027f) * t) + 1.421413741f) * t - 0.284496736f) * t + 0.254829592f;
    float y = 1.0f - p * t * __expf(-ax * ax);
    return copysignf(y, x);
}

static __device__ __forceinline__ float gelu_f(float x) {
    return 0.5f * x * (1.0f + fast_erf(x * 0.7071067811865476f));
}

static __device__ __forceinline__ f32x16 mfma32(bf16x8 a, bf16x8 b, f32x16 c) {
    return __builtin_amdgcn_mfma_f32_32x32x16_bf16(a, b, c, 0, 0, 0);
}

// stage one 16KB weight chunk [256 cols][32 k] bf16 into LDS, bank-swizzled.
// LDS slot s (16B units) holds global (col,kseg) with s = (col*4+kseg) ^ ((col>>1)&7).
// LDS dest stays linear (global_load_lds constraint); source address pre-swizzled.
static __device__ __forceinline__ void stage_swz(const unsigned short* __restrict__ src,
                                                 unsigned short* lds_base, int tid) {
#pragma unroll
    for (int i = 0; i < 4; i++) {
        int s = i * 256 + tid;
        int m = (s >> 3) & 7;
        int low = (s & 7) ^ m;
        int col = ((s >> 3) << 1) | (low >> 2);
        int kseg = low & 3;
        const unsigned short* gp = src + (col << 8) + (kseg << 3);
        unsigned short* lp = lds_base + ((i * 256 + (tid & ~63)) << 3);
        __builtin_amdgcn_global_load_lds((gas_t)(const void*)gp, (las_t)(void*)lp, 16, 0, 0);
    }
}

// ---------------- prep kernels ----------------

// w1t[e][c][k] = W1[e][k][c], k in [0,256)  (tiled coalesced transpose)
__global__ void k_w1t(const float* __restrict__ W1, unsigned short* __restrict__ w1t) {
    __shared__ float tile[64][65];
    int e = blockIdx.x >> 4, kt = (blockIdx.x >> 2) & 3, ct = blockIdx.x & 3;
    int k0 = kt << 6, c0 = ct << 6;
    const float* src = W1 + ((size_t)e << 18) + ((size_t)k0 << 8) + c0;
    int r = threadIdx.x >> 6, col = threadIdx.x & 63;
#pragma unroll
    for (int i = 0; i < 16; i++)
        tile[r + i * 4][col] = src[(size_t)(r + i * 4) * 256 + col];
    __syncthreads();
    unsigned short* dst = w1t + (e << 16) + (c0 << 8) + k0;
#pragma unroll
    for (int i = 0; i < 16; i++)
        dst[(r + i * 4) * 256 + col] = f2bf(tile[col][r + i * 4]);
}

// w2t[e][f][c] = W2[e][c][f]
__global__ void k_w2t(const float* __restrict__ W2, unsigned short* __restrict__ w2t) {
    __shared__ float tile[64][65];
    int e = blockIdx.x >> 4, ct = (blockIdx.x >> 2) & 3, ft = blockIdx.x & 3;
    int c0 = ct << 6, f0 = ft << 6;
    const float* src = W2 + ((size_t)e << 16) + ((size_t)c0 << 8) + f0;
    int r = threadIdx.x >> 6, col = threadIdx.x & 63;
#pragma unroll
    for (int i = 0; i < 16; i++)
        tile[r + i * 4][col] = src[(size_t)(r + i * 4) * 256 + col];
    __syncthreads();
    unsigned short* dst = w2t + (e << 16) + (f0 << 8) + c0;
#pragma unroll
    for (int i = 0; i < 16; i++)
        dst[(r + i * 4) * 256 + col] = f2bf(tile[col][r + i * 4]);
}

// v2[e][c] = sum_f W2[e,c,f]*We[e,f];  c2[e] = sum_f b2[e,f]*We[e,f] + be[e]
__global__ void k_v2(const float* __restrict__ W2, const float* __restrict__ We,
                     const float* __restrict__ b2, const float* __restrict__ be,
                     float* __restrict__ v2, float* __restrict__ c2) {
    __shared__ float sm[4];
    int e = blockIdx.x >> 8, c = blockIdx.x & 255, f = threadIdx.x;
    float wef = We[(e << 8) + f];
    float v = W2[((((e << 8) + c) << 8)) + f] * wef;
#pragma unroll
    for (int m = 32; m >= 1; m >>= 1) v += __shfl_xor(v, m);
    if ((f & 63) == 0) sm[f >> 6] = v;
    __syncthreads();
    if (f == 0) v2[(e << 8) + c] = sm[0] + sm[1] + sm[2] + sm[3];
    if (c == 0) {
        __syncthreads();
        float u = b2[(e << 8) + f] * wef;
#pragma unroll
        for (int m = 32; m >= 1; m >>= 1) u += __shfl_xor(u, m);
        if ((f & 63) == 0) sm[f >> 6] = u;
        __syncthreads();
        if (f == 0) c2[e] = sm[0] + sm[1] + sm[2] + sm[3] + be[e];
    }
}

// ---------------- LN + masked stats (+ x -> bf16 conversion fused) ----------------

__global__ void k_stats(const float* __restrict__ x, const int* __restrict__ mask,
                        const float* __restrict__ lnw, const float* __restrict__ lnb,
                        float* __restrict__ S1, float* __restrict__ S2, float* __restrict__ ncnt,
                        unsigned short* __restrict__ xb) {
    int b = blockIdx.x >> 6;
    int chunk = blockIdx.x & 63;
    int wid = threadIdx.x >> 6, lane = threadIdx.x & 63;
    int c0 = lane << 2;
    float4 w4 = *reinterpret_cast<const float4*>(lnw + c0);
    float4 b4 = *reinterpret_cast<const float4*>(lnb + c0);
    float a1[4] = {0,0,0,0}, a2[4] = {0,0,0,0};
    int cnt = 0;
    int tbase = chunk * 128;
    for (int r = wid; r < 128; r += 4) {
        int row = b * T_ + tbase + r;
        float4 xv = *reinterpret_cast<const float4*>(x + (size_t)row * C_ + c0);
        ushort4 o;
        o.x = f2bf(xv.x); o.y = f2bf(xv.y); o.z = f2bf(xv.z); o.w = f2bf(xv.w);
        *reinterpret_cast<ushort4*>(xb + (size_t)row * C_ + c0) = o;
        float s1 = xv.x + xv.y + xv.z + xv.w;
        float s2 = xv.x*xv.x + xv.y*xv.y + xv.z*xv.z + xv.w*xv.w;
#pragma unroll
        for (int m = 1; m < 64; m <<= 1) { s1 += __shfl_xor(s1, m); s2 += __shfl_xor(s2, m); }
        if (mask[row]) {
            float mu = s1 * (1.f / C_);
            float var = s2 * (1.f / C_) - mu * mu;
            float rs = rsqrtf(var + 1e-5f);
            float hv;
            hv = (xv.x - mu) * rs * w4.x + b4.x; a1[0] += hv; a2[0] += hv * hv;
            hv = (xv.y - mu) * rs * w4.y + b4.y; a1[1] += hv; a2[1] += hv * hv;
            hv = (xv.z - mu) * rs * w4.z + b4.z; a1[2] += hv; a2[2] += hv * hv;
            hv = (xv.w - mu) * rs * w4.w + b4.w; a1[3] += hv; a2[3] += hv * hv;
            cnt++;
        }
    }
    __shared__ float red[4][256];
    __shared__ int rc[4];
#pragma unroll
    for (int j = 0; j < 4; j++) red[wid][c0 + j] = a1[j];
    if (lane == 0) rc[wid] = cnt;
    __syncthreads();
    int ch = threadIdx.x;
    float s = red[0][ch] + red[1][ch] + red[2][ch] + red[3][ch];
    atomicAdd(&S1[(b << 8) + ch], s);
    if (threadIdx.x == 0) atomicAdd(&ncnt[b], (float)(rc[0] + rc[1] + rc[2] + rc[3]));
    __syncthreads();
#pragma unroll
    for (int j = 0; j < 4; j++) red[wid][c0 + j] = a2[j];
    __syncthreads();
    s = red[0][ch] + red[1][ch] + red[2][ch] + red[3][ch];
    atomicAdd(&S2[(b << 8) + ch], s);
}

__global__ void k_stats_fin(const float* __restrict__ S1, const float* __restrict__ S2,
                            const float* __restrict__ ncnt, float* __restrict__ stats) {
    int b = blockIdx.x, c = threadIdx.x;
    float n = fmaxf(ncnt[b], 1.f);
    float mean = S1[(b << 8) + c] / n;
    float var_b = fmaxf(S2[(b << 8) + c] / n - mean * mean, 0.f);
    float var_u = (n > 1.f) ? (var_b * (n / fmaxf(n - 1.f, 1e-9f))) : var_b;
    float std_u = fmaxf(sqrtf(var_u), 1e-9f);
    stats[b * 768 + 0 * 256 + c] = mean;
    stats[b * 768 + 1 * 256 + c] = std_u;
    stats[b * 768 + 2 * 256 + c] = var_u;
}

__global__ void k_bias(const float* __restrict__ W1, const float* __restrict__ b1,
                       const float* __restrict__ stats, float* __restrict__ bias) {
    int b = blockIdx.x >> 3, e = blockIdx.x & 7, c = threadIdx.x;
    __shared__ float sm[768];
    for (int i = threadIdx.x; i < 768; i += 256) sm[i] = stats[b * 768 + i];
    __syncthreads();
    const float* w = W1 + (size_t)e * 1024 * 256;
    float acc = b1[(e << 8) + c];
#pragma unroll 4
    for (int j = 0; j < 256; j++) {
        acc += sm[j]       * w[(256 + j) * 256 + c];
        acc += sm[256 + j] * w[(512 + j) * 256 + c];
        acc += sm[512 + j] * w[(768 + j) * 256 + c];
    }
    bias[((b << 3) + e) * 256 + c] = acc;
}

// ---------------- fused: GEMM1 + gelu + energies + online softmax + GEMM2 ----------------
// block = 64 rows, 4 waves (2m x 2n), 32x32x16 MFMA; wave = 32 rows x 128 cols.
// A-fragments loaded on demand from xb (L1/L2-resident) to keep register demand
// under the 256 VGPR+AGPR unified budget at 2 waves/SIMD (round-4 spilled).

__global__ __launch_bounds__(256, 2) void k_fused(
    const unsigned short* __restrict__ xb, const unsigned short* __restrict__ w1t,
    const unsigned short* __restrict__ w2t, const float* __restrict__ bias,
    const float* __restrict__ v2, const float* __restrict__ c2,
    const int* __restrict__ mask, const float* __restrict__ b2,
    const float* __restrict__ log_beta, const float* __restrict__ prior,
    float* __restrict__ out) {
    __shared__ unsigned short stg[2][8192];   // 2 x 16KB weight chunks (swizzled)
    __shared__ unsigned short h1s[16384];     // [64][256] bf16, row-swizzled
    __shared__ float b2s[2048];               // [8][256]
    __shared__ float nbs[64][8];
    __shared__ float enp[2][64];
    __shared__ float rs_[64], us_[64], sinv_[64];

    int row0 = blockIdx.x << 6;
    int b = row0 >> 13;
    int tid = threadIdx.x;
    int w = tid >> 6, lane = tid & 63;
    int mw = w >> 1, nw = w & 1;
    int nwo = nw << 7;                        // wave's column base (N-half)
    int c_ = lane & 31, hi = lane >> 5;

    for (int i = tid; i < 2048; i += 256) b2s[i] = b2[i];
    int mreg = 0; float m_run = -3.0e38f; float beta = 0.f;
    if (tid < 64) { mreg = mask[row0 + tid]; beta = __expf(log_beta[0]); }

    // per-lane A row pointer (frag for (kk,kf): arow + kk*32 + kf*16)
    const unsigned short* arow = xb + (size_t)(row0 + (mw << 5) + c_) * C_ + (hi << 3);

    f32x16 acc2[4], accG[4];
#pragma unroll
    for (int nt = 0; nt < 4; nt++)
#pragma unroll
        for (int r = 0; r < 16; r++) acc2[nt][r] = 0.f;

    stage_swz(w1t, stg[0], tid);
    __syncthreads();

    int pc = 0;
    for (int e = 0; e < E_; e++) {
        // ---- GEMM1: accG = x @ W1x + bias_fold ----
        const float* bre = bias + (((b << 3) + e) << 8);
#pragma unroll
        for (int nt = 0; nt < 4; nt++) {
            float bv = bre[nwo + (nt << 5) + c_];
#pragma unroll
            for (int r = 0; r < 16; r++) accG[nt][r] = bv;
        }
#pragma unroll
        for (int kk = 0; kk < 8; kk++) {
            int nc = pc + 1;
            if (nc < 128) {
                const unsigned short* nsrc = (((nc >> 3) & 1) ? w2t : w1t) + ((nc >> 4) << 16) + ((nc & 7) << 5);
                stage_swz(nsrc, stg[nc & 1], tid);
            }
            const unsigned short* bs = stg[pc & 1];
#pragma unroll
            for (int kf = 0; kf < 2; kf++) {
                bf16x8 a = *reinterpret_cast<const bf16x8*>(arow + (kk << 5) + (kf << 4));
#pragma unroll
                for (int nt = 0; nt < 4; nt++) {
                    int col = nwo + (nt << 5) + c_;
                    int slot = ((col << 2) + (kf << 1) + hi) ^ ((c_ >> 1) & 7);
                    bf16x8 bf = *reinterpret_cast<const bf16x8*>(bs + (slot << 3));
                    accG[nt] = mfma32(a, bf, accG[nt]);
                }
            }
            __syncthreads();
            pc++;
        }
        // ---- gelu (in place) + energy partials ----
        float v2v[4];
#pragma unroll
        for (int nt = 0; nt < 4; nt++) v2v[nt] = v2[(e << 8) + nwo + (nt << 5) + c_];
        float epr[16];
#pragma unroll
        for (int r = 0; r < 16; r++) {
            float sum = 0.f;
#pragma unroll
            for (int nt = 0; nt < 4; nt++) {
                float g = gelu_f(accG[nt][r]);
                accG[nt][r] = g;
                sum += g * v2v[nt];
            }
            epr[r] = sum;
        }
#pragma unroll
        for (int m = 1; m < 32; m <<= 1)
#pragma unroll
            for (int r = 0; r < 16; r++) epr[r] += __shfl_xor(epr[r], m);
        // write unscaled gelu(h1) to LDS (row-swizzled), and energy partials
#pragma unroll
        for (int r = 0; r < 16; r++) {
            int rowl = (mw << 5) + (r & 3) + ((r >> 2) << 3) + (hi << 2);
#pragma unroll
            for (int nt = 0; nt < 4; nt++) {
                int col = nwo + (nt << 5) + c_;
                int byteoff = ((rowl << 9) + (col << 1)) ^ ((rowl & 7) << 4);
                *reinterpret_cast<unsigned short*>(reinterpret_cast<char*>(h1s) + byteoff) = f2bf(accG[nt][r]);
            }
            if (c_ == 0) enp[nw][rowl] = epr[r];
        }
        __syncthreads();
        // ---- online softmax update (threads 0..63, row = tid) ----
        if (tid < 64) {
            float en = enp[0][tid] + enp[1][tid] + c2[e];
            float nb = -beta * (en + prior[e]);
            nbs[tid][e] = nb;
            float mn = fmaxf(m_run, nb);
            rs_[tid] = __expf(m_run - mn);
            us_[tid] = __expf(nb - mn);
            m_run = mn;
        }
        __syncthreads();
        // ---- GEMM2: accG = gelu_h1 @ W2 + b2 ----
#pragma unroll
        for (int nt = 0; nt < 4; nt++) {
            float bv = b2s[(e << 8) + nwo + (nt << 5) + c_];
#pragma unroll
            for (int r = 0; r < 16; r++) accG[nt][r] = bv;
        }
        int rowA = (mw << 5) + c_;
        int rswz = (rowA & 7) << 4;
        const char* h1b = reinterpret_cast<const char*>(h1s) + (rowA << 9);
#pragma unroll
        for (int kk = 0; kk < 8; kk++) {
            int nc = pc + 1;
            if (nc < 128) {
                const unsigned short* nsrc = (((nc >> 3) & 1) ? w2t : w1t) + ((nc >> 4) << 16) + ((nc & 7) << 5);
                stage_swz(nsrc, stg[nc & 1], tid);
            }
            const unsigned short* bs = stg[pc & 1];
#pragma unroll
            for (int kf = 0; kf < 2; kf++) {
                int k2 = (kk << 6) + (kf << 5) + (hi << 4);
                bf16x8 a2 = *reinterpret_cast<const bf16x8*>(h1b + (k2 ^ rswz));
#pragma unroll
                for (int nt = 0; nt < 4; nt++) {
                    int col = nwo + (nt << 5) + c_;
                    int slot = ((col << 2) + (kf << 1) + hi) ^ ((c_ >> 1) & 7);
                    bf16x8 bf = *reinterpret_cast<const bf16x8*>(bs + (slot << 3));
                    accG[nt] = mfma32(a2, bf, accG[nt]);
                }
            }
            __syncthreads();
            pc++;
        }
        // ---- merge: acc2 = acc2*r + u*accG ----
#pragma unroll
        for (int r = 0; r < 16; r++) {
            int rowl = (mw << 5) + (r & 3) + ((r >> 2) << 3) + (hi << 2);
            float rr = rs_[rowl];
            float uu = us_[rowl];
#pragma unroll
            for (int nt = 0; nt < 4; nt++)
                acc2[nt][r] = acc2[nt][r] * rr + uu * accG[nt][r];
        }
    }
    // ---- epilogue: normalize by partition function, mask ----
    if (tid < 64) {
        float s = 0.f;
#pragma unroll
        for (int e = 0; e < 8; e++) s += __expf(nbs[tid][e] - m_run);
        sinv_[tid] = mreg ? (1.0f / s) : 0.f;
    }
    __syncthreads();
#pragma unroll
    for (int r = 0; r < 16; r++) {
        int rowl = (mw << 5) + (r & 3) + ((r >> 2) << 3) + (hi << 2);
        float si = sinv_[rowl];
        float* orow = out + (size_t)(row0 + rowl) * C_;
#pragma unroll
        for (int nt = 0; nt < 4; nt++)
            __builtin_nontemporal_store(acc2[nt][r] * si, orow + nwo + (nt << 5) + c_);
    }
}

// ---------------- launch ----------------

extern "C" void kernel_launch(void* const* d_in, const int* in_sizes, int n_in,
                              void* d_out, int out_size, void* d_ws, size_t ws_size,
                              hipStream_t stream) {
    (void)in_sizes; (void)n_in; (void)out_size; (void)ws_size;
    const float* x        = (const float*)d_in[0];
    const int*   mask     = (const int*)d_in[1];
    const float* lnw      = (const float*)d_in[2];
    const float* lnb      = (const float*)d_in[3];
    const float* W1       = (const float*)d_in[4];
    const float* b1       = (const float*)d_in[5];
    const float* W2       = (const float*)d_in[6];
    const float* b2       = (const float*)d_in[7];
    const float* We       = (const float*)d_in[8];
    const float* be       = (const float*)d_in[9];
    const float* log_beta = (const float*)d_in[10];
    const float* prior    = (const float*)d_in[11];
    float* out = (float*)d_out;
    char* ws = (char*)d_ws;

    constexpr size_t OFF_XB    = 0;                       // 16 MB
    constexpr size_t OFF_W1T   = 16777216;                // 1 MB
    constexpr size_t OFF_W2T   = 17825792;                // 1 MB
    constexpr size_t OFF_V2    = 18874368;                // 8 KB
    constexpr size_t OFF_C2    = 18882560;                // 32 B
    constexpr size_t OFF_S1    = 18882592;                // 4 KB
    constexpr size_t OFF_S2    = 18886688;                // 4 KB
    constexpr size_t OFF_N     = 18890784;                // 16 B
    constexpr size_t OFF_STATS = 18890800;                // 12 KB
    constexpr size_t OFF_BIAS  = 18903088;                // 32 KB

    unsigned short* xb  = (unsigned short*)(ws + OFF_XB);
    unsigned short* w1t = (unsigned short*)(ws + OFF_W1T);
    unsigned short* w2t = (unsigned short*)(ws + OFF_W2T);
    float* v2    = (float*)(ws + OFF_V2);
    float* c2    = (float*)(ws + OFF_C2);
    float* S1    = (float*)(ws + OFF_S1);
    float* S2    = (float*)(ws + OFF_S2);
    float* ncnt  = (float*)(ws + OFF_N);
    float* stats = (float*)(ws + OFF_STATS);
    float* bias  = (float*)(ws + OFF_BIAS);

    hipMemsetAsync(ws + OFF_S1, 0, 4096 + 4096 + 16, stream);

    k_w1t<<<128, 256, 0, stream>>>(W1, w1t);
    k_w2t<<<128, 256, 0, stream>>>(W2, w2t);
    k_v2<<<2048, 256, 0, stream>>>(W2, We, b2, be, v2, c2);
    k_stats<<<256, 256, 0, stream>>>(x, mask, lnw, lnb, S1, S2, ncnt, xb);
    k_stats_fin<<<4, 256, 0, stream>>>(S1, S2, ncnt, stats);
    k_bias<<<32, 256, 0, stream>>>(W1, b1, stats, bias);
    k_fused<<<512, 256, 0, stream>>>(xb, w1t, w2t, bias, v2, c2, mask, b2, log_beta, prior, out);
}